// Round 1
// baseline (157.090 us; speedup 1.0000x reference)
//
#include <hip/hip_runtime.h>
#include <stdint.h>

#define NQ   12
#define DIM  4096   // 2^12 amplitudes
#define TPB  256

// ---------- host-computed GF(2) circuit structure ----------
struct PassP {
  uint16_t v[4];     // pair XOR-vectors (columns of A^-k)
  uint16_t m[4];     // role parity masks (rows of A^k)
  uint16_t cmb[16];  // cmb[n] = XOR of v[i] over set bits of n (linear)
  uint8_t  np[8];    // non-pivot bit positions (coset representative deposit)
  uint8_t  layer;    // qparams layer (1 or 2)
  uint8_t  wbase;    // first wire of this group of 4
  uint8_t  pad[2];
};
struct KP {
  PassP    pass[6];
  uint16_t ro_mask[12]; // rows of A^3 (readout parity masks)
  uint16_t ro_lut[16];  // bit i = parity((ro_mask[i]>>8) & j)
};

static void bmm(uint32_t* C, const uint32_t* A, const uint32_t* B) {
  // z = A(Bx): row_i(C) = XOR_{j in row_i(A)} row_j(B)
  for (int i = 0; i < NQ; ++i) {
    uint32_t r = 0;
    for (int j = 0; j < NQ; ++j) if ((A[i] >> j) & 1u) r ^= B[j];
    C[i] = r;
  }
}
static void binv(const uint32_t* M, uint32_t* Inv) {
  uint32_t A[NQ], I[NQ];
  for (int i = 0; i < NQ; ++i) { A[i] = M[i]; I[i] = 1u << i; }
  for (int c = 0; c < NQ; ++c) {
    int piv = -1;
    for (int r = c; r < NQ; ++r) if ((A[r] >> c) & 1u) { piv = r; break; }
    if (piv < 0) continue; // invertible in practice
    uint32_t ta = A[c]; A[c] = A[piv]; A[piv] = ta;
    uint32_t ti = I[c]; I[c] = I[piv]; I[piv] = ti;
    for (int r = 0; r < NQ; ++r)
      if (r != c && ((A[r] >> c) & 1u)) { A[r] ^= A[c]; I[r] ^= I[c]; }
  }
  for (int i = 0; i < NQ; ++i) Inv[i] = I[i];
}

static void build_kp(KP& kp) {
  // CNOT chain as bit-matrix: q[i+1]^=q[i] for i=0..10, then q[0]^=q[11]
  // -> new q0 = x1^...^x11 ; new q_i = x0^...^x_i (i>=1)
  uint32_t A[NQ];
  A[0] = 0xFFEu;
  for (int i = 1; i < NQ; ++i) A[i] = (1u << (i + 1)) - 1u;
  uint32_t A2[NQ], A3[NQ], Ai[NQ], A2i[NQ];
  bmm(A2, A, A); bmm(A3, A2, A);
  binv(A, Ai); binv(A2, A2i);

  for (int p = 0; p < 6; ++p) {
    int L = (p < 3) ? 1 : 2;
    int wb = (p % 3) * 4;
    const uint32_t* M  = (L == 1) ? A  : A2;
    const uint32_t* Mi = (L == 1) ? Ai : A2i;
    uint32_t v[4], m[4];
    for (int i = 0; i < 4; ++i) {
      int w = wb + i;
      uint32_t col = 0;
      for (int r = 0; r < NQ; ++r) col |= ((Mi[r] >> w) & 1u) << r; // v = A^-k e_w
      v[i] = col; m[i] = M[w];
    }
    // Gaussian elimination (pivot = highest set bit) to find 8 free bit positions
    uint32_t redv[4]; int pbit[4]; uint32_t pivmask = 0;
    for (int i = 0; i < 4; ++i) {
      redv[i] = v[i];
      for (int k = 0; k < i; ++k) if ((redv[i] >> pbit[k]) & 1u) redv[i] ^= redv[k];
      pbit[i] = 31 - __builtin_clz(redv[i]);
      pivmask |= 1u << pbit[i];
    }
    int c = 0;
    for (int b = 0; b < NQ; ++b)
      if (!((pivmask >> b) & 1u)) kp.pass[p].np[c++] = (uint8_t)b;
    for (int n = 0; n < 16; ++n) {
      uint32_t cm = 0;
      for (int i = 0; i < 4; ++i) if ((n >> i) & 1) cm ^= v[i];
      kp.pass[p].cmb[n] = (uint16_t)cm;
    }
    for (int i = 0; i < 4; ++i) { kp.pass[p].v[i] = (uint16_t)v[i]; kp.pass[p].m[i] = (uint16_t)m[i]; }
    kp.pass[p].layer = (uint8_t)L; kp.pass[p].wbase = (uint8_t)wb;
    kp.pass[p].pad[0] = kp.pass[p].pad[1] = 0;
  }
  for (int i = 0; i < NQ; ++i) kp.ro_mask[i] = (uint16_t)A3[i];
  for (int j = 0; j < 16; ++j) {
    uint32_t bits = 0;
    for (int i = 0; i < NQ; ++i)
      bits |= (uint32_t)(__builtin_popcount((A3[i] >> 8) & (uint32_t)j) & 1) << i;
    kp.ro_lut[j] = (uint16_t)bits;
  }
}

// ---------- device ----------
__device__ __forceinline__ float2 cmul(float2 a, float2 b) {
  return make_float2(a.x * b.x - a.y * b.y, a.x * b.y + a.y * b.x);
}
__device__ __forceinline__ float2 cadd(float2 a, float2 b) {
  return make_float2(a.x + b.x, a.y + b.y);
}

__global__ __launch_bounds__(TPB) void hqc_kernel(
    const float* __restrict__ x,  const float* __restrict__ W1, const float* __restrict__ b1,
    const float* __restrict__ W2, const float* __restrict__ b2,
    const float* __restrict__ W3, const float* __restrict__ b3,
    const float* __restrict__ qp, const float* __restrict__ P1, const float* __restrict__ c1,
    const float* __restrict__ P2, const float* __restrict__ c2,
    const float* __restrict__ P3, const float* __restrict__ c3,
    float* __restrict__ out, KP kp)
{
  __shared__ float2 st[DIM];          // 32 KB statevector
  __shared__ float2 gg[3][NQ][4];     // fused 2x2 gates; [0][w][0..1] = encoded column
  __shared__ float  sb[48];           // h1[0:16] h2[16:32] ang[32:44]
  __shared__ float  red[4][NQ];
  __shared__ float  qv[NQ], o1v[16], o2v[8];

  const int s = blockIdx.x;
  const int t = threadIdx.x;

  // ---- pre-MLP: x -> angles ----
  if (t < 16) {
    float a = b1[t];
    #pragma unroll
    for (int j = 0; j < 6; ++j) a = fmaf(W1[t * 6 + j], x[s * 6 + j], a);
    sb[t] = fmaxf(a, 0.f);
  }
  __syncthreads();
  if (t < 16) {
    float a = b2[t];
    #pragma unroll
    for (int j = 0; j < 16; ++j) a = fmaf(W2[t * 16 + j], sb[j], a);
    sb[16 + t] = fmaxf(a, 0.f);
  }
  __syncthreads();
  if (t < NQ) {
    float a = b3[t];
    #pragma unroll
    for (int j = 0; j < 16; ++j) a = fmaf(W3[t * 16 + j], sb[16 + j], a);
    sb[32 + t] = a;
  }
  __syncthreads();

  // ---- build fused gates U = RZ(p2)RY(p1)RX(p0); layer0 folded with encoding RY|0> ----
  if (t < 36) {
    int l = t / 12, w = t % 12;
    float p0 = qp[(l * 12 + w) * 3 + 0];
    float p1 = qp[(l * 12 + w) * 3 + 1];
    float p2 = qp[(l * 12 + w) * 3 + 2];
    float cx, sx, cy, sy, cz, sz;
    sincosf(0.5f * p0, &sx, &cx);
    sincosf(0.5f * p1, &sy, &cy);
    sincosf(0.5f * p2, &sz, &cz);
    // M = RY*RX
    float2 M00 = make_float2( cy * cx,  sy * sx);
    float2 M01 = make_float2(-sy * cx, -cy * sx);
    float2 M10 = make_float2( sy * cx, -cy * sx);
    float2 M11 = make_float2( cy * cx, -sy * sx);
    float2 ez  = make_float2(cz, -sz);   // e^{-i p2/2}
    float2 ezc = make_float2(cz,  sz);
    float2 U00 = cmul(ez, M00),  U01 = cmul(ez, M01);
    float2 U10 = cmul(ezc, M10), U11 = cmul(ezc, M11);
    if (l == 0) {
      float ca, sa; sincosf(0.5f * sb[32 + w], &sa, &ca);
      gg[0][w][0] = make_float2(U00.x * ca + U01.x * sa, U00.y * ca + U01.y * sa);
      gg[0][w][1] = make_float2(U10.x * ca + U11.x * sa, U10.y * ca + U11.y * sa);
    } else {
      gg[l][w][0] = U00; gg[l][w][1] = U01; gg[l][w][2] = U10; gg[l][w][3] = U11;
    }
  }
  __syncthreads();

  // ---- build product state: idx = t | (j<<8), amp = prod_i c_i[bit_i(idx)] ----
  {
    float2 common = make_float2(1.f, 0.f);
    #pragma unroll
    for (int i = 0; i < 8; ++i) common = cmul(common, gg[0][i][(t >> i) & 1]);
    float2 l16[16];
    l16[0] = common;
    #pragma unroll
    for (int i = 0; i < 4; ++i) {
      float2 c0 = gg[0][8 + i][0], c1v = gg[0][8 + i][1];
      #pragma unroll
      for (int j = 0; j < (1 << i); ++j) {
        l16[j | (1 << i)] = cmul(l16[j], c1v);
        l16[j]            = cmul(l16[j], c0);
      }
    }
    #pragma unroll
    for (int j = 0; j < 16; ++j) st[t | (j << 8)] = l16[j];
  }
  __syncthreads();

  // ---- 6 generalized-gate passes (4 fused wires per pass, coset in registers) ----
  #pragma unroll 1
  for (int p = 0; p < 6; ++p) {
    const PassP& pp = kp.pass[p];
    int rep = 0;
    #pragma unroll
    for (int k = 0; k < 8; ++k) rep |= ((t >> k) & 1) << pp.np[k];
    int rho = 0;
    #pragma unroll
    for (int i = 0; i < 4; ++i) rho |= (__popc(pp.m[i] & rep) & 1) << i;
    int base = rep;
    #pragma unroll
    for (int i = 0; i < 4; ++i) if ((rho >> i) & 1) base ^= pp.v[i];
    int addr[16];
    #pragma unroll
    for (int r = 0; r < 16; ++r) addr[r] = base ^ pp.cmb[r];
    float2 sl[16];
    #pragma unroll
    for (int r = 0; r < 16; ++r) sl[r] = st[addr[r]];
    const int gl = pp.layer, wb = pp.wbase;
    #pragma unroll
    for (int i = 0; i < 4; ++i) {
      float2 U00 = gg[gl][wb + i][0], U01 = gg[gl][wb + i][1];
      float2 U10 = gg[gl][wb + i][2], U11 = gg[gl][wb + i][3];
      #pragma unroll
      for (int r = 0; r < 16; ++r) {
        if (r & (1 << i)) continue;
        int r1 = r | (1 << i);
        float2 a0 = sl[r], a1 = sl[r1];
        sl[r]  = cadd(cmul(U00, a0), cmul(U01, a1));
        sl[r1] = cadd(cmul(U10, a0), cmul(U11, a1));
      }
    }
    #pragma unroll
    for (int r = 0; r < 16; ++r) st[addr[r]] = sl[r];
    __syncthreads();
  }

  // ---- readout: ev_i = sum |amp|^2 * (1 - 2*parity(ro_mask_i & idx)) ----
  float ev[NQ];
  #pragma unroll
  for (int i = 0; i < NQ; ++i) ev[i] = 0.f;
  int pb = 0;
  #pragma unroll
  for (int i = 0; i < NQ; ++i) pb |= (__popc(kp.ro_mask[i] & t) & 1) << i;
  #pragma unroll
  for (int j = 0; j < 16; ++j) {
    float2 a = st[t | (j << 8)];
    float pr = a.x * a.x + a.y * a.y;
    int bits = pb ^ kp.ro_lut[j];
    #pragma unroll
    for (int i = 0; i < NQ; ++i) ev[i] += ((bits >> i) & 1) ? -pr : pr;
  }
  #pragma unroll
  for (int off = 32; off >= 1; off >>= 1) {
    #pragma unroll
    for (int i = 0; i < NQ; ++i) ev[i] += __shfl_xor(ev[i], off, 64);
  }
  const int wv = t >> 6;
  if ((t & 63) == 0) {
    #pragma unroll
    for (int i = 0; i < NQ; ++i) red[wv][i] = ev[i];
  }
  __syncthreads();
  if (t < NQ) qv[t] = red[0][t] + red[1][t] + red[2][t] + red[3][t];
  __syncthreads();

  // ---- post-MLP ----
  if (t < 16) {
    float a = c1[t];
    #pragma unroll
    for (int j = 0; j < NQ; ++j) a = fmaf(P1[t * NQ + j], qv[j], a);
    o1v[t] = fmaxf(a, 0.f);
  }
  __syncthreads();
  if (t < 8) {
    float a = c2[t];
    #pragma unroll
    for (int j = 0; j < 16; ++j) a = fmaf(P2[t * 16 + j], o1v[j], a);
    o2v[t] = fmaxf(a, 0.f);
  }
  __syncthreads();
  if (t == 0) {
    float a = c3[0];
    #pragma unroll
    for (int j = 0; j < 8; ++j) a = fmaf(P3[j], o2v[j], a);
    out[s] = 1.f / (1.f + expf(-a));
  }
}

extern "C" void kernel_launch(void* const* d_in, const int* in_sizes, int n_in,
                              void* d_out, int out_size, void* d_ws, size_t ws_size,
                              hipStream_t stream) {
  (void)in_sizes; (void)n_in; (void)d_ws; (void)ws_size;
  KP kp;
  build_kp(kp);
  hqc_kernel<<<out_size, TPB, 0, stream>>>(
      (const float*)d_in[0],  (const float*)d_in[1],  (const float*)d_in[2],
      (const float*)d_in[3],  (const float*)d_in[4],  (const float*)d_in[5],
      (const float*)d_in[6],  (const float*)d_in[7],  (const float*)d_in[8],
      (const float*)d_in[9],  (const float*)d_in[10], (const float*)d_in[11],
      (const float*)d_in[12], (const float*)d_in[13],
      (float*)d_out, kp);
}

// Round 2
// 107.393 us; speedup vs baseline: 1.4628x; 1.4628x over previous
//
#include <hip/hip_runtime.h>
#include <stdint.h>

#define NQ   12
#define DIM  4096   // 2^12 amplitudes
#define TPB  256

typedef float v2f __attribute__((ext_vector_type(2)));

// ---------- compile-time GF(2) circuit structure ----------
struct PassP {
  uint16_t v[4];     // pair XOR-vectors (columns of A^-k)
  uint16_t m[4];     // role parity masks (rows of A^k)
  uint16_t cmb[16];  // cmb[n] = XOR of v[i] over set bits of n
  uint8_t  np[8];    // free-bit positions (thread-bit k -> index bit np[k])
  uint8_t  layer;    // qparams layer (1 or 2)
  uint8_t  wbase;    // first wire of this group of 4
};
struct KP {
  PassP    pass[6];
  uint16_t ro_mask[12]; // rows of A^3 (readout parity masks)
};

constexpr int chbit(uint32_t x) { int b = -1; for (int i = 0; i < 32; ++i) if ((x >> i) & 1u) b = i; return b; }

constexpr void bmm(uint32_t* C, const uint32_t* A, const uint32_t* B) {
  for (int i = 0; i < NQ; ++i) {
    uint32_t r = 0;
    for (int j = 0; j < NQ; ++j) if ((A[i] >> j) & 1u) r ^= B[j];
    C[i] = r;
  }
}
constexpr void binv(const uint32_t* M, uint32_t* Inv) {
  uint32_t A[NQ] = {}, I[NQ] = {};
  for (int i = 0; i < NQ; ++i) { A[i] = M[i]; I[i] = 1u << i; }
  for (int c = 0; c < NQ; ++c) {
    int piv = -1;
    for (int r = c; r < NQ; ++r) if ((A[r] >> c) & 1u) { piv = r; break; }
    if (piv < 0) continue;
    uint32_t ta = A[c]; A[c] = A[piv]; A[piv] = ta;
    uint32_t ti = I[c]; I[c] = I[piv]; I[piv] = ti;
    for (int r = 0; r < NQ; ++r)
      if (r != c && ((A[r] >> c) & 1u)) { A[r] ^= A[c]; I[r] ^= I[c]; }
  }
  for (int i = 0; i < NQ; ++i) Inv[i] = I[i];
}

constexpr KP make_kp() {
  KP kp{};
  // CNOT chain: q[i+1]^=q[i] for i=0..10, then q[0]^=q[11]
  uint32_t A[NQ] = {};
  A[0] = 0xFFEu;
  for (int i = 1; i < NQ; ++i) A[i] = (1u << (i + 1)) - 1u;
  uint32_t A2[NQ] = {}, A3[NQ] = {}, Ai[NQ] = {}, A2i[NQ] = {};
  bmm(A2, A, A); bmm(A3, A2, A);
  binv(A, Ai); binv(A2, A2i);

  for (int p = 0; p < 6; ++p) {
    int L = (p < 3) ? 1 : 2;
    int wb = (p % 3) * 4;
    const uint32_t* M  = (L == 1) ? A  : A2;
    const uint32_t* Mi = (L == 1) ? Ai : A2i;
    uint32_t v[4] = {}, m[4] = {};
    for (int i = 0; i < 4; ++i) {
      int w = wb + i;
      uint32_t col = 0;
      for (int r = 0; r < NQ; ++r) col |= ((Mi[r] >> w) & 1u) << r;
      v[i] = col; m[i] = M[w];
    }
    // pivot bits of span{v} -> 8 free (non-pivot) bit positions
    uint32_t redv[4] = {}; int pbit[4] = {}; uint32_t pivmask = 0;
    for (int i = 0; i < 4; ++i) {
      redv[i] = v[i];
      for (int k = 0; k < i; ++k) if ((redv[i] >> pbit[k]) & 1u) redv[i] ^= redv[k];
      pbit[i] = chbit(redv[i]);
      pivmask |= 1u << pbit[i];
    }
    uint8_t np0[8] = {};
    int c = 0;
    for (int b = 0; b < NQ; ++b)
      if (!((pivmask >> b) & 1u)) np0[c++] = (uint8_t)b;

    // ---- bank-conflict-aware ordering of np ----
    // base = B*rep over GF(2), B = I ^ sum v_i m_i^T. ds_*_b64 is conflict-free
    // iff lanes 0..15 (thread bits 0..3 -> np[0..3]) give 16 distinct (addr&15),
    // i.e. low-4 rows of B restricted to {np[0..3]} have rank 4. Search C(8,4).
    uint32_t Brow[4] = {};
    for (int r = 0; r < 4; ++r) {
      uint32_t row = 1u << r;
      for (int i = 0; i < 4; ++i) if ((v[i] >> r) & 1u) row ^= m[i];
      Brow[r] = row;
    }
    uint32_t colsig[8] = {};
    for (int cc = 0; cc < 8; ++cc) {
      uint32_t s = 0;
      for (int r = 0; r < 4; ++r) s |= ((Brow[r] >> np0[cc]) & 1u) << r;
      colsig[cc] = s;
    }
    int b0 = 0, b1 = 1, b2 = 2, b3 = 3, bestrank = -1;
    bool found = false;
    for (int a = 0; a < 8 && !found; ++a)
      for (int b = a + 1; b < 8 && !found; ++b)
        for (int cx = b + 1; cx < 8 && !found; ++cx)
          for (int d = cx + 1; d < 8 && !found; ++d) {
            uint32_t rows2[4] = {}; int rnk = 0;
            int idxs[4] = {a, b, cx, d};
            for (int q = 0; q < 4; ++q) {
              uint32_t x = colsig[idxs[q]];
              for (int bit = 3; bit >= 0; --bit) {
                if (!((x >> bit) & 1u)) continue;
                if (rows2[bit]) { x ^= rows2[bit]; }
                else { rows2[bit] = x; ++rnk; break; }
              }
            }
            if (rnk > bestrank) {
              bestrank = rnk; b0 = a; b1 = b; b2 = cx; b3 = d;
              if (rnk == 4) found = true;
            }
          }
    uint8_t npn[8] = {};
    npn[0] = np0[b0]; npn[1] = np0[b1]; npn[2] = np0[b2]; npn[3] = np0[b3];
    int cn = 4;
    for (int cc = 0; cc < 8; ++cc)
      if (cc != b0 && cc != b1 && cc != b2 && cc != b3) npn[cn++] = np0[cc];
    for (int cc = 0; cc < 8; ++cc) kp.pass[p].np[cc] = npn[cc];

    for (int n = 0; n < 16; ++n) {
      uint32_t cm = 0;
      for (int i = 0; i < 4; ++i) if ((n >> i) & 1) cm ^= v[i];
      kp.pass[p].cmb[n] = (uint16_t)cm;
    }
    for (int i = 0; i < 4; ++i) { kp.pass[p].v[i] = (uint16_t)v[i]; kp.pass[p].m[i] = (uint16_t)m[i]; }
    kp.pass[p].layer = (uint8_t)L; kp.pass[p].wbase = (uint8_t)wb;
  }
  for (int i = 0; i < NQ; ++i) kp.ro_mask[i] = (uint16_t)A3[i];
  return kp;
}

constexpr KP kpc = make_kp();

// ---------- kernel ----------
__global__ __launch_bounds__(TPB, 4) void hqc_kernel(
    const float* __restrict__ x,  const float* __restrict__ W1, const float* __restrict__ b1,
    const float* __restrict__ W2, const float* __restrict__ b2,
    const float* __restrict__ W3, const float* __restrict__ b3,
    const float* __restrict__ qp, const float* __restrict__ P1, const float* __restrict__ c1,
    const float* __restrict__ P2, const float* __restrict__ c2,
    const float* __restrict__ P3, const float* __restrict__ c3,
    float* __restrict__ out)
{
  __shared__ v2f  st[DIM];           // 32 KB statevector
  __shared__ v2f  gxx[3][NQ][4];     // packed gate entries {x,x}
  __shared__ v2f  gmy[3][NQ][4];     // packed gate entries {-y,y}
  __shared__ float sb[48];           // h1[0:16] h2[16:32] ang[32:44]
  __shared__ float red[4][NQ];
  __shared__ float qv[NQ], o1v[16], o2v[8];

  const int s = blockIdx.x;
  const int t = threadIdx.x;

  // ---- pre-MLP: x -> angles ----
  if (t < 16) {
    float a = b1[t];
    #pragma unroll
    for (int j = 0; j < 6; ++j) a = fmaf(W1[t * 6 + j], x[s * 6 + j], a);
    sb[t] = fmaxf(a, 0.f);
  }
  __syncthreads();
  if (t < 16) {
    float a = b2[t];
    #pragma unroll
    for (int j = 0; j < 16; ++j) a = fmaf(W2[t * 16 + j], sb[j], a);
    sb[16 + t] = fmaxf(a, 0.f);
  }
  __syncthreads();
  if (t < NQ) {
    float a = b3[t];
    #pragma unroll
    for (int j = 0; j < 16; ++j) a = fmaf(W3[t * 16 + j], sb[16 + j], a);
    sb[32 + t] = a;
  }
  __syncthreads();

  // ---- fused gates U = RZ(p2)RY(p1)RX(p0); layer0 folded with encoding RY|0> ----
  if (t < 36) {
    int l = t / 12, w = t % 12;
    float p0 = qp[(l * 12 + w) * 3 + 0];
    float p1 = qp[(l * 12 + w) * 3 + 1];
    float p2 = qp[(l * 12 + w) * 3 + 2];
    float cx, sx, cy, sy, cz, sz;
    sincosf(0.5f * p0, &sx, &cx);
    sincosf(0.5f * p1, &sy, &cy);
    sincosf(0.5f * p2, &sz, &cz);
    // M = RY*RX (complex entries as scalar pairs)
    float M00x =  cy * cx, M00y =  sy * sx;
    float M01x = -sy * cx, M01y = -cy * sx;
    float M10x =  sy * cx, M10y = -cy * sx;
    float M11x =  cy * cx, M11y = -sy * sx;
    // U = diag(e^{-i p2/2}, e^{+i p2/2}) * M
    float U00x = cz * M00x + sz * M00y, U00y = cz * M00y - sz * M00x;
    float U01x = cz * M01x + sz * M01y, U01y = cz * M01y - sz * M01x;
    float U10x = cz * M10x - sz * M10y, U10y = cz * M10y + sz * M10x;
    float U11x = cz * M11x - sz * M11y, U11y = cz * M11y + sz * M11x;
    if (l == 0) {
      float ca, sa; sincosf(0.5f * sb[32 + w], &sa, &ca);
      float c0x = U00x * ca + U01x * sa, c0y = U00y * ca + U01y * sa;
      float c1x = U10x * ca + U11x * sa, c1y = U10y * ca + U11y * sa;
      gxx[0][w][0] = (v2f){c0x, c0x}; gmy[0][w][0] = (v2f){-c0y, c0y};
      gxx[0][w][1] = (v2f){c1x, c1x}; gmy[0][w][1] = (v2f){-c1y, c1y};
    } else {
      gxx[l][w][0] = (v2f){U00x, U00x}; gmy[l][w][0] = (v2f){-U00y, U00y};
      gxx[l][w][1] = (v2f){U01x, U01x}; gmy[l][w][1] = (v2f){-U01y, U01y};
      gxx[l][w][2] = (v2f){U10x, U10x}; gmy[l][w][2] = (v2f){-U10y, U10y};
      gxx[l][w][3] = (v2f){U11x, U11x}; gmy[l][w][3] = (v2f){-U11y, U11y};
    }
  }
  __syncthreads();

  // ---- product state: idx = t | (j<<8), amp = prod_i c_i[bit_i(idx)] ----
  {
    v2f acc = (v2f){1.f, 0.f};
    #pragma unroll
    for (int i = 0; i < 8; ++i) {
      int b = (t >> i) & 1;
      v2f xx = gxx[0][i][b], my = gmy[0][i][b];
      acc = xx * acc + my * acc.yx;
    }
    v2f l16[16];
    l16[0] = acc;
    #pragma unroll
    for (int i = 0; i < 4; ++i) {
      v2f xx0 = gxx[0][8 + i][0], my0 = gmy[0][8 + i][0];
      v2f xx1 = gxx[0][8 + i][1], my1 = gmy[0][8 + i][1];
      #pragma unroll
      for (int j = 0; j < (1 << i); ++j) {
        v2f a = l16[j];
        l16[j | (1 << i)] = xx1 * a + my1 * a.yx;
        l16[j]            = xx0 * a + my0 * a.yx;
      }
    }
    #pragma unroll
    for (int j = 0; j < 16; ++j) st[t | (j << 8)] = l16[j];
  }
  __syncthreads();

  // ---- 6 generalized-gate passes (all structure constants are literals) ----
  #pragma unroll
  for (int p = 0; p < 6; ++p) {
    const PassP& pp = kpc.pass[p];
    int rep = 0;
    #pragma unroll
    for (int k = 0; k < 8; ++k) rep |= ((t >> k) & 1) << pp.np[k];
    int rho = 0;
    #pragma unroll
    for (int i = 0; i < 4; ++i) rho |= (__popc(pp.m[i] & rep) & 1) << i;
    int base = rep;
    #pragma unroll
    for (int i = 0; i < 4; ++i) if ((rho >> i) & 1) base ^= pp.v[i];
    int addr[16];
    #pragma unroll
    for (int r = 0; r < 16; ++r) addr[r] = base ^ pp.cmb[r];
    v2f sl[16];
    #pragma unroll
    for (int r = 0; r < 16; ++r) sl[r] = st[addr[r]];
    const int gl = pp.layer, wb = pp.wbase;
    #pragma unroll
    for (int i = 0; i < 4; ++i) {
      v2f xxA = gxx[gl][wb + i][0], myA = gmy[gl][wb + i][0];
      v2f xxB = gxx[gl][wb + i][1], myB = gmy[gl][wb + i][1];
      v2f xxC = gxx[gl][wb + i][2], myC = gmy[gl][wb + i][2];
      v2f xxD = gxx[gl][wb + i][3], myD = gmy[gl][wb + i][3];
      #pragma unroll
      for (int r = 0; r < 16; ++r) {
        if (r & (1 << i)) continue;
        int r1 = r | (1 << i);
        v2f a0 = sl[r], a1 = sl[r1];
        v2f a0s = a0.yx, a1s = a1.yx;
        sl[r]  = xxA * a0 + myA * a0s + xxB * a1 + myB * a1s;
        sl[r1] = xxC * a0 + myC * a0s + xxD * a1 + myD * a1s;
      }
    }
    #pragma unroll
    for (int r = 0; r < 16; ++r) st[addr[r]] = sl[r];
    __syncthreads();
  }

  // ---- readout via 4-bit Walsh-Hadamard over the high index bits ----
  float pr[16];
  #pragma unroll
  for (int j = 0; j < 16; ++j) {
    v2f a = st[t | (j << 8)];
    pr[j] = a.x * a.x + a.y * a.y;
  }
  #pragma unroll
  for (int g = 1; g < 16; g <<= 1) {
    #pragma unroll
    for (int j = 0; j < 16; ++j) {
      if (j & g) continue;
      float u = pr[j], w2 = pr[j | g];
      pr[j] = u + w2; pr[j | g] = u - w2;
    }
  }
  int pb = 0;
  #pragma unroll
  for (int i = 0; i < NQ; ++i) pb |= (__popc(kpc.ro_mask[i] & t) & 1) << i;
  float ev[NQ];
  #pragma unroll
  for (int i = 0; i < NQ; ++i) {
    float h = pr[(kpc.ro_mask[i] >> 8) & 15];  // constexpr index
    ev[i] = ((pb >> i) & 1) ? -h : h;
  }
  #pragma unroll
  for (int off = 32; off >= 1; off >>= 1) {
    #pragma unroll
    for (int i = 0; i < NQ; ++i) ev[i] += __shfl_xor(ev[i], off, 64);
  }
  const int wv = t >> 6;
  if ((t & 63) == 0) {
    #pragma unroll
    for (int i = 0; i < NQ; ++i) red[wv][i] = ev[i];
  }
  __syncthreads();
  if (t < NQ) qv[t] = red[0][t] + red[1][t] + red[2][t] + red[3][t];
  __syncthreads();

  // ---- post-MLP ----
  if (t < 16) {
    float a = c1[t];
    #pragma unroll
    for (int j = 0; j < NQ; ++j) a = fmaf(P1[t * NQ + j], qv[j], a);
    o1v[t] = fmaxf(a, 0.f);
  }
  __syncthreads();
  if (t < 8) {
    float a = c2[t];
    #pragma unroll
    for (int j = 0; j < 16; ++j) a = fmaf(P2[t * 16 + j], o1v[j], a);
    o2v[t] = fmaxf(a, 0.f);
  }
  __syncthreads();
  if (t == 0) {
    float a = c3[0];
    #pragma unroll
    for (int j = 0; j < 8; ++j) a = fmaf(P3[j], o2v[j], a);
    out[s] = 1.f / (1.f + expf(-a));
  }
}

extern "C" void kernel_launch(void* const* d_in, const int* in_sizes, int n_in,
                              void* d_out, int out_size, void* d_ws, size_t ws_size,
                              hipStream_t stream) {
  (void)in_sizes; (void)n_in; (void)d_ws; (void)ws_size;
  hqc_kernel<<<out_size, TPB, 0, stream>>>(
      (const float*)d_in[0],  (const float*)d_in[1],  (const float*)d_in[2],
      (const float*)d_in[3],  (const float*)d_in[4],  (const float*)d_in[5],
      (const float*)d_in[6],  (const float*)d_in[7],  (const float*)d_in[8],
      (const float*)d_in[9],  (const float*)d_in[10], (const float*)d_in[11],
      (const float*)d_in[12], (const float*)d_in[13],
      (float*)d_out);
}